// Round 2
// baseline (833.897 us; speedup 1.0000x reference)
//
#include <hip/hip_runtime.h>
#include <math.h>

// Problem constants
#define BB 256          // batch
#define CC 256          // channels
#define MN 196          // H*W
#define TRI 32896       // C*(C+1)/2

// ---------------------------------------------------------------------------
// Per-row means: one wave per (b,c) row of 196 floats. Full batch, runs once.
// ---------------------------------------------------------------------------
__global__ __launch_bounds__(256) void mean_kernel(const float* __restrict__ x,
                                                   float* __restrict__ mu) {
    int wave = (blockIdx.x * 256 + threadIdx.x) >> 6;   // 0 .. B*C-1
    int lane = threadIdx.x & 63;
    const float* row = x + (size_t)wave * MN;
    float s = row[lane] + row[lane + 64] + row[lane + 128];
    if (lane < MN - 192) s += row[lane + 192];
    #pragma unroll
    for (int off = 32; off > 0; off >>= 1) s += __shfl_down(s, off, 64);
    if (lane == 0) mu[wave] = s * (1.0f / MN);
}

// ---------------------------------------------------------------------------
// Covariance: cov = (X X^T)/M - mu mu^T for batches [b0, b0+g).
// 128x128 tiles, upper tiles only (t00,t01,t11), t01 mirror-written so cov is
// EXACTLY symmetric. LDS [m][r] (k-major) so compute reads are float4, 2-way.
// ---------------------------------------------------------------------------
__global__ __launch_bounds__(256) void cov_kernel(const float* __restrict__ x,
                                                  const float* __restrict__ mu,
                                                  float* __restrict__ cov, int b0) {
    __shared__ __align__(16) float As[49][132];
    __shared__ __align__(16) float Bs[49][132];
    const int bl = blockIdx.x / 3;          // local batch (slot index)
    const int t  = blockIdx.x - 3 * bl;
    const int bg = b0 + bl;                 // global batch
    const int ti = (t == 2) ? 1 : 0;
    const int tj = (t == 0) ? 0 : 1;
    const int tid = threadIdx.x;
    const int tx = tid & 15, ty = tid >> 4;
    const float* xa = x + (size_t)bg * CC * MN + (size_t)ti * 128 * MN;
    const float* xb = x + (size_t)bg * CC * MN + (size_t)tj * 128 * MN;

    float acc[8][8];
    #pragma unroll
    for (int i = 0; i < 8; ++i)
        #pragma unroll
        for (int j = 0; j < 8; ++j) acc[i][j] = 0.0f;

    #pragma unroll 1
    for (int chunk = 0; chunk < 4; ++chunk) {
        const int m0 = chunk * 49;
        __syncthreads();
        #pragma unroll 5
        for (int it = 0; it < 25; ++it) {
            int f = tid + 256 * it;
            if (f < 128 * 49) {
                int r = f / 49;
                int m = f - r * 49;
                As[m][r] = xa[(size_t)r * MN + m0 + m];
                Bs[m][r] = xb[(size_t)r * MN + m0 + m];
            }
        }
        __syncthreads();
        #pragma unroll 7
        for (int m = 0; m < 49; ++m) {
            float4 a0 = *(const float4*)&As[m][4 * ty];
            float4 a1 = *(const float4*)&As[m][64 + 4 * ty];
            float4 b0v = *(const float4*)&Bs[m][4 * tx];
            float4 b1v = *(const float4*)&Bs[m][64 + 4 * tx];
            float av[8] = {a0.x, a0.y, a0.z, a0.w, a1.x, a1.y, a1.z, a1.w};
            float bv[8] = {b0v.x, b0v.y, b0v.z, b0v.w, b1v.x, b1v.y, b1v.z, b1v.w};
            #pragma unroll
            for (int i = 0; i < 8; ++i)
                #pragma unroll
                for (int j = 0; j < 8; ++j)
                    acc[i][j] = fmaf(av[i], bv[j], acc[i][j]);
        }
    }

    int rl[8], cl[8];
    #pragma unroll
    for (int i = 0; i < 4; ++i) {
        rl[i] = 4 * ty + i; rl[i + 4] = 64 + 4 * ty + i;
        cl[i] = 4 * tx + i; cl[i + 4] = 64 + 4 * tx + i;
    }
    const float* mub = mu + bg * CC;
    float mur[8], muc[8];
    #pragma unroll
    for (int i = 0; i < 8; ++i) {
        mur[i] = mub[ti * 128 + rl[i]];
        muc[i] = mub[tj * 128 + cl[i]];
    }
    #pragma unroll
    for (int i = 0; i < 8; ++i)
        #pragma unroll
        for (int j = 0; j < 8; ++j)
            acc[i][j] = acc[i][j] * (1.0f / MN) - mur[i] * muc[j];

    float* cb = cov + (size_t)bl * CC * CC;
    #pragma unroll
    for (int i = 0; i < 8; ++i) {
        int gi = ti * 128 + rl[i];
        float4 lo = {acc[i][0], acc[i][1], acc[i][2], acc[i][3]};
        float4 hi = {acc[i][4], acc[i][5], acc[i][6], acc[i][7]};
        *(float4*)&cb[(size_t)gi * CC + tj * 128 + 4 * tx] = lo;
        *(float4*)&cb[(size_t)gi * CC + tj * 128 + 64 + 4 * tx] = hi;
    }
    if (ti != tj) {
        #pragma unroll
        for (int j = 0; j < 8; ++j) {
            int gj = tj * 128 + cl[j];
            float4 lo = {acc[0][j], acc[1][j], acc[2][j], acc[3][j]};
            float4 hi = {acc[4][j], acc[5][j], acc[6][j], acc[7][j]};
            *(float4*)&cb[(size_t)gj * CC + ti * 128 + 4 * ty] = lo;
            *(float4*)&cb[(size_t)gj * CC + ti * 128 + 64 + 4 * ty] = hi;
        }
    }
}

// ---------------------------------------------------------------------------
// trace of cov (local slot) -> inv = 1/n, snorm = sqrt(n), invs = 1/sqrt(n)
// indexed by GLOBAL batch (arrays live in d_out tail scratch).
// ---------------------------------------------------------------------------
__global__ __launch_bounds__(256) void trace_kernel(const float* __restrict__ cov,
                                                    float* __restrict__ inv,
                                                    float* __restrict__ snorm,
                                                    float* __restrict__ invs, int b0) {
    __shared__ float red[256];
    int bl = blockIdx.x, i = threadIdx.x;
    red[i] = cov[((size_t)bl * CC + i) * CC + i];
    __syncthreads();
    for (int s = 128; s > 0; s >>= 1) {
        if (i < s) red[i] += red[i + s];
        __syncthreads();
    }
    if (i == 0) {
        float n = red[0];
        int bg = b0 + bl;
        inv[bg] = 1.0f / n;
        float sq = sqrtf(n);
        snorm[bg] = sq;
        invs[bg] = 1.0f / sq;
    }
}

// ---------------------------------------------------------------------------
// prep: A = cov / normA, in place on slot s0.
// ---------------------------------------------------------------------------
__global__ __launch_bounds__(256) void prep_kernel(float* __restrict__ s0,
                                                   const float* __restrict__ inv, int b0) {
    int f4 = blockIdx.x * 256 + threadIdx.x;   // float4 index within chunk
    int bl = f4 >> 14;                         // C*C/4 = 16384 float4 per batch
    float iv = inv[b0 + bl];
    float4 v = ((const float4*)s0)[f4];
    float4 a = {v.x * iv, v.y * iv, v.z * iv, v.w * iv};
    ((float4*)s0)[f4] = a;
}

// ---------------------------------------------------------------------------
// Batched symmetric GEMM with fused affine epilogue:
//   C = alpha*(A@B) + beta*E + diag*I      (alpha,beta optionally * Sg[bg])
// FINAL variant: out(triu) = acc (no scalars).
// 128x128 tile / 256 threads / 8x8 per-thread. All operands symmetric, staged
// k-major via symmetry: coalesced float4 loads, conflict-free float4 LDS.
// Upper tiles only (t00,t01,t11); t01 mirror-written (non-final).
// ---------------------------------------------------------------------------
template <bool FINAL>
__global__ __launch_bounds__(256) void ns_gemm_kernel(const float* __restrict__ Ag,
                                                      const float* __restrict__ Bg,
                                                      const float* __restrict__ Eg,
                                                      float* __restrict__ Cg,
                                                      const float alpha0,
                                                      const float beta0,
                                                      const float diag_add,
                                                      const float* __restrict__ Sg,
                                                      int b0) {
    __shared__ __align__(16) float As[16][132];
    __shared__ __align__(16) float Bs[16][132];
    const int bl = blockIdx.x / 3;
    const int t  = blockIdx.x - 3 * bl;
    const int bg = b0 + bl;
    const int ti = (t == 2) ? 1 : 0;
    const int tj = (t == 0) ? 0 : 1;
    const int tid = threadIdx.x;
    const int tx = tid & 15, ty = tid >> 4;
    const int kk0 = tid >> 5;            // 0..7
    const int c0  = (tid & 31) * 4;      // 0..124
    const float* Ab = Ag + (size_t)bl * CC * CC + ti * 128;
    const float* Bb = Bg + (size_t)bl * CC * CC + tj * 128;

    float acc[8][8];
    #pragma unroll
    for (int i = 0; i < 8; ++i)
        #pragma unroll
        for (int j = 0; j < 8; ++j) acc[i][j] = 0.0f;

    #pragma unroll 1
    for (int k0 = 0; k0 < CC; k0 += 16) {
        __syncthreads();
        *(float4*)&As[kk0][c0]     = *(const float4*)(Ab + (size_t)(k0 + kk0) * CC + c0);
        *(float4*)&As[kk0 + 8][c0] = *(const float4*)(Ab + (size_t)(k0 + kk0 + 8) * CC + c0);
        *(float4*)&Bs[kk0][c0]     = *(const float4*)(Bb + (size_t)(k0 + kk0) * CC + c0);
        *(float4*)&Bs[kk0 + 8][c0] = *(const float4*)(Bb + (size_t)(k0 + kk0 + 8) * CC + c0);
        __syncthreads();
        #pragma unroll
        for (int kk = 0; kk < 16; ++kk) {
            float4 a0 = *(const float4*)&As[kk][4 * ty];
            float4 a1 = *(const float4*)&As[kk][64 + 4 * ty];
            float4 b0v = *(const float4*)&Bs[kk][4 * tx];
            float4 b1v = *(const float4*)&Bs[kk][64 + 4 * tx];
            float av[8] = {a0.x, a0.y, a0.z, a0.w, a1.x, a1.y, a1.z, a1.w};
            float bv[8] = {b0v.x, b0v.y, b0v.z, b0v.w, b1v.x, b1v.y, b1v.z, b1v.w};
            #pragma unroll
            for (int i = 0; i < 8; ++i)
                #pragma unroll
                for (int j = 0; j < 8; ++j)
                    acc[i][j] = fmaf(av[i], bv[j], acc[i][j]);
        }
    }

    int rl[8], cl[8];
    #pragma unroll
    for (int i = 0; i < 4; ++i) {
        rl[i] = 4 * ty + i; rl[i + 4] = 64 + 4 * ty + i;
        cl[i] = 4 * tx + i; cl[i + 4] = 64 + 4 * tx + i;
    }

    if (!FINAL) {
        float s = (Sg != nullptr) ? Sg[bg] : 1.0f;
        float al = alpha0 * s;
        float be = beta0 * s;
        float ev[8][8];
        if (Eg != nullptr) {
            const float* Eb = Eg + (size_t)bl * CC * CC;
            #pragma unroll
            for (int i = 0; i < 8; ++i) {
                int gi = ti * 128 + rl[i];
                float4 lo = *(const float4*)&Eb[(size_t)gi * CC + tj * 128 + 4 * tx];
                float4 hi = *(const float4*)&Eb[(size_t)gi * CC + tj * 128 + 64 + 4 * tx];
                ev[i][0] = lo.x; ev[i][1] = lo.y; ev[i][2] = lo.z; ev[i][3] = lo.w;
                ev[i][4] = hi.x; ev[i][5] = hi.y; ev[i][6] = hi.z; ev[i][7] = hi.w;
            }
        } else {
            #pragma unroll
            for (int i = 0; i < 8; ++i)
                #pragma unroll
                for (int j = 0; j < 8; ++j) ev[i][j] = 0.0f;
        }
        #pragma unroll
        for (int i = 0; i < 8; ++i) {
            int gi = ti * 128 + rl[i];
            #pragma unroll
            for (int j = 0; j < 8; ++j) {
                int gj = tj * 128 + cl[j];
                acc[i][j] = al * acc[i][j] + be * ev[i][j] + ((gi == gj) ? diag_add : 0.0f);
            }
        }
        float* cb = Cg + (size_t)bl * CC * CC;
        #pragma unroll
        for (int i = 0; i < 8; ++i) {
            int gi = ti * 128 + rl[i];
            float4 lo = {acc[i][0], acc[i][1], acc[i][2], acc[i][3]};
            float4 hi = {acc[i][4], acc[i][5], acc[i][6], acc[i][7]};
            *(float4*)&cb[(size_t)gi * CC + tj * 128 + 4 * tx] = lo;
            *(float4*)&cb[(size_t)gi * CC + tj * 128 + 64 + 4 * tx] = hi;
        }
        if (ti != tj) {
            #pragma unroll
            for (int j = 0; j < 8; ++j) {
                int gj = tj * 128 + cl[j];
                float4 lo = {acc[0][j], acc[1][j], acc[2][j], acc[3][j]};
                float4 hi = {acc[4][j], acc[5][j], acc[6][j], acc[7][j]};
                *(float4*)&cb[(size_t)gj * CC + ti * 128 + 4 * ty] = lo;
                *(float4*)&cb[(size_t)gj * CC + ti * 128 + 64 + 4 * ty] = hi;
            }
        }
    } else {
        float* ob = Cg + (size_t)bg * TRI;
        #pragma unroll
        for (int i = 0; i < 8; ++i) {
            int gi = ti * 128 + rl[i];
            int rowbase = gi * CC - (gi * (gi - 1)) / 2 - gi;  // + gj -> triu index
            #pragma unroll
            for (int j = 0; j < 8; ++j) {
                int gj = tj * 128 + cl[j];
                if (gj >= gi) ob[rowbase + gj] = acc[i][j];
            }
        }
    }
}

// ---------------------------------------------------------------------------
// Schedule per chunk of g batches (4 slots of g MiB each in d_ws):
//   A  = cov/n                              (cov+trace+prep, s0)
//   Y1 = -0.5 A@A  + 1.5 A                  -> s1
//   ZY1= 0.25 A@Y1 - 0.75 Y1 + 1.5 I        -> s2
//   Y2'= sqrt(n) * (Y1@ZY1)                 -> s3   [A,Y1 still live]
//   Z2'= (1/sqrt(n)) * (-0.5 ZY1@A + 1.5 ZY1) -> s1 [Y1 dead]
//   T  = -0.5 Z2'@Y2' + 1.5 I               -> s0   [A dead]
//   out= triu(Y2'@T)                        -> d_out [scale folded into Y2']
// Small arrays (mu/inv/snorm/invs) live in the TAIL of d_out, which is only
// overwritten by the very last GEMM of the last chunk (stream-ordered safe).
// ---------------------------------------------------------------------------
extern "C" void kernel_launch(void* const* d_in, const int* in_sizes, int n_in,
                              void* d_out, int out_size, void* d_ws, size_t ws_size,
                              hipStream_t stream) {
    const float* x = (const float*)d_in[0];
    float* out = (float*)d_out;
    float* ws = (float*)d_ws;

    const int SCR = BB * CC + 3 * BB;          // 66304 floats of scalar scratch
    float* mu    = out + (out_size - SCR);
    float* inv   = mu + BB * CC;
    float* snorm = inv + BB;
    float* invs  = snorm + BB;

    // adaptive chunk: largest power-of-two g with 4 fp32 slots fitting d_ws
    size_t per_b = 4ull * CC * CC * sizeof(float);   // 1 MiB per batch elem
    int gmax = (int)(ws_size / per_b);
    int g = 1;
    while (g * 2 <= gmax && g * 2 <= BB) g *= 2;

    size_t slotf = (size_t)g * CC * CC;
    float* s0 = ws;
    float* s1 = ws + slotf;
    float* s2 = ws + 2 * slotf;
    float* s3 = ws + 3 * slotf;

    mean_kernel<<<BB * CC / 4, 256, 0, stream>>>(x, mu);

    for (int b0 = 0; b0 < BB; b0 += g) {
        cov_kernel<<<g * 3, 256, 0, stream>>>(x, mu, s0, b0);
        trace_kernel<<<g, 256, 0, stream>>>(s0, inv, snorm, invs, b0);
        prep_kernel<<<g * 64, 256, 0, stream>>>(s0, inv, b0);
        // Y1 = -0.5*(A@A) + 1.5*A
        ns_gemm_kernel<false><<<g * 3, 256, 0, stream>>>(s0, s0, s0, s1, -0.5f, 1.5f, 0.0f, nullptr, b0);
        // ZY1 = 0.25*(A@Y1) - 0.75*Y1 + 1.5*I
        ns_gemm_kernel<false><<<g * 3, 256, 0, stream>>>(s0, s1, s1, s2, 0.25f, -0.75f, 1.5f, nullptr, b0);
        // Y2' = snorm * (Y1@ZY1)
        ns_gemm_kernel<false><<<g * 3, 256, 0, stream>>>(s1, s2, nullptr, s3, 1.0f, 0.0f, 0.0f, snorm, b0);
        // Z2' = invs * (-0.5*(ZY1@A) + 1.5*ZY1)
        ns_gemm_kernel<false><<<g * 3, 256, 0, stream>>>(s2, s0, s2, s1, -0.5f, 1.5f, 0.0f, invs, b0);
        // T = -0.5*(Z2'@Y2') + 1.5*I
        ns_gemm_kernel<false><<<g * 3, 256, 0, stream>>>(s1, s3, nullptr, s0, -0.5f, 0.0f, 1.5f, nullptr, b0);
        // out = triu(Y2'@T)
        ns_gemm_kernel<true><<<g * 3, 256, 0, stream>>>(s3, s0, nullptr, out, 1.0f, 0.0f, 0.0f, nullptr, b0);
    }
}